// Round 11
// baseline (190.210 us; speedup 1.0000x reference)
//
#include <hip/hip_runtime.h>

// PositionalWordEmbedding: out[b,s,d] = W[x[b,s]][d] + pe[s][d]
// B=32, S=4096, D=256, VOCAB=50257. Output fp32, 128 MiB -> memory-bound.
//
// R7:  79 us @ 33% HBM, Occ 33% -> latency-bound (1024 blocks).
// R9:  BPT 4, grid 8192, nt stores: pwe ~58 us. Floor is ~32-40 us
//      (201 MB @ 6.3 TB/s; fill hits 6.5 TB/s pure-write on this chip).
// R10: BPT 2 (2x gather chains, 2x trig/output): FLAT -> neither ILP nor
//      hidden-trig volume is the limiter.
// R11: split off the transcendentals entirely. Kernel 1 builds the 4 MB
//      PE table in d_ws (~2 us). Kernel 2 is pure streaming: pe load
//      (cached), scalar token load (readfirstlane -> s_load path),
//      coalesced W-row gather, add, nt store. Tests whether the 200-inst
//      powf/sincos body was degrading memory scheduling in the hot loop.

#define SEQ   4096
#define DIM   256
#define BATCH 32
#define D4    (DIM / 4)      // 64 float4 per row
#define BPT   4              // batches per thread (R9 config)
#define NGRP  (BATCH / BPT)  // 8 batch-groups
#define SD    (SEQ * D4)     // 262144 = 2^18 (s,d4) slots
#define PE_BYTES ((size_t)SEQ * DIM * 4)   // 4 MiB

typedef float f32x4 __attribute__((ext_vector_type(4)));

__device__ __forceinline__ f32x4 pe_value(int s, int d4) {
    int d0 = d4 * 4;
    float f0 = powf(10000.0f, -(float)d0       / (float)DIM);
    float f2 = powf(10000.0f, -(float)(d0 + 2) / (float)DIM);
    float p  = (float)s;
    float s0, c0, s2, c2;
    sincosf(p * f0, &s0, &c0);
    sincosf(p * f2, &s2, &c2);
    f32x4 pe;
    pe.x = s0; pe.y = c0; pe.z = s2; pe.w = c2;
    return pe;
}

// Kernel 1: build pe[s][d] table, 262144 float4s = 4 MiB.
__global__ __launch_bounds__(256)
void pe_build_kernel(f32x4* __restrict__ pe4) {
    int sd = blockIdx.x * blockDim.x + threadIdx.x;   // 0 .. SD-1
    pe4[sd] = pe_value(sd >> 6, sd & 63);
}

// Kernel 2: pure-streaming gather+add+store.
__global__ __launch_bounds__(256)
void pwe_main_kernel(const int* __restrict__ x,
                     const f32x4* __restrict__ W4,
                     const f32x4* __restrict__ pe4,
                     f32x4* __restrict__ out4) {
    int tid = blockIdx.x * blockDim.x + threadIdx.x;   // 0 .. SD*NGRP-1
    int sd  = tid & (SD - 1);
    int bg  = tid >> 18;          // batch group 0..7
    int s   = __builtin_amdgcn_readfirstlane(tid >> 6) & (SEQ - 1); // uniform
    int d4  = sd & 63;

    f32x4 pe = pe4[sd];           // coalesced, L2/L3-resident (4 MiB)

    const int b0 = bg * BPT;
    int tok[BPT];
    #pragma unroll
    for (int i = 0; i < BPT; ++i)
        tok[i] = x[(b0 + i) * SEQ + s];               // SGPR-uniform -> s_load

    #pragma unroll
    for (int i = 0; i < BPT; ++i) {
        f32x4 w = W4[(size_t)tok[i] * D4 + d4];       // coalesced row gather
        f32x4 o = w + pe;
        __builtin_nontemporal_store(
            o, &out4[((size_t)(b0 + i) * SEQ + s) * D4 + d4]);
    }
}

// Fallback (ws too small): R9 kernel with inline trig.
__global__ __launch_bounds__(256)
void pwe_inline_kernel(const int* __restrict__ x,
                       const f32x4* __restrict__ W4,
                       f32x4* __restrict__ out4) {
    int tid = blockIdx.x * blockDim.x + threadIdx.x;
    int sd  = tid & (SD - 1);
    int bg  = tid >> 18;
    int s   = sd >> 6;
    int d4  = sd & 63;
    f32x4 pe = pe_value(s, d4);
    const int b0 = bg * BPT;
    int tok[BPT];
    #pragma unroll
    for (int i = 0; i < BPT; ++i)
        tok[i] = x[(b0 + i) * SEQ + s];
    #pragma unroll
    for (int i = 0; i < BPT; ++i) {
        f32x4 w = W4[(size_t)tok[i] * D4 + d4];
        f32x4 o = w + pe;
        __builtin_nontemporal_store(
            o, &out4[((size_t)(b0 + i) * SEQ + s) * D4 + d4]);
    }
}

extern "C" void kernel_launch(void* const* d_in, const int* in_sizes, int n_in,
                              void* d_out, int out_size, void* d_ws, size_t ws_size,
                              hipStream_t stream) {
    const int*   x = (const int*)d_in[0];      // [32, 4096] token ids
    const float* W = (const float*)d_in[1];    // [50257, 256] fp32
    float*     out = (float*)d_out;            // [32, 4096, 256] fp32

    const int block = 256;
    const int grid_main = SD * NGRP / block;   // 8192 blocks

    if (ws_size >= PE_BYTES) {
        f32x4* pe4 = (f32x4*)d_ws;
        pe_build_kernel<<<SD / block, block, 0, stream>>>(pe4);
        pwe_main_kernel<<<grid_main, block, 0, stream>>>(
            x, (const f32x4*)W, pe4, (f32x4*)out);
    } else {
        pwe_inline_kernel<<<grid_main, block, 0, stream>>>(
            x, (const f32x4*)W, (f32x4*)out);
    }
}

// Round 12
// 179.770 us; speedup vs baseline: 1.0581x; 1.0581x over previous
//
#include <hip/hip_runtime.h>

// PositionalWordEmbedding: out[b,s,d] = W[x[b,s]][d] + pe[s][d]
// B=32, S=4096, D=256, VOCAB=50257. Output fp32, 128 MiB -> memory-bound.
//
// R7:  79 us @ 33% HBM, Occ 33% -> latency-bound (1024 blocks).
// R9:  BPT 4, grid 8192, nt stores: pwe ~58 us (harness 205->184).
// R10: BPT 2: FLAT -> gather-chain ILP not the limiter.
// R11: PE table in ws (no trig in hot loop): FLAT+launch overhead ->
//      VALU/trig not the limiter either.
// R12: single-variable ablation of the OTHER thing R9 changed:
//      nontemporal stores. fill (6.5 TB/s) and the m13 copy ubench
//      (6.29 TB/s, mixed R/W like us) both use PLAIN stores; we're at
//      3.5 TB/s effective. Hypothesis: nt bypasses L2/write-coalescing
//      and throttles the store stream. This kernel == R9 minus nt.

#define SEQ   4096
#define DIM   256
#define BATCH 32
#define D4    (DIM / 4)      // 64 float4 per row
#define BPT   4              // batches per thread
#define NGRP  (BATCH / BPT)  // 8 batch-groups
#define SD    (SEQ * D4)     // 262144 = 2^18 (s,d4) slots

typedef float f32x4 __attribute__((ext_vector_type(4)));

__global__ __launch_bounds__(256)
void pwe_kernel(const int* __restrict__ x,
                const f32x4* __restrict__ W4,
                f32x4* __restrict__ out4) {
    int tid = blockIdx.x * blockDim.x + threadIdx.x;   // 0 .. SD*NGRP-1
    int sd  = tid & (SD - 1);     // (s,d4), wave-aligned: lanes share s
    int bg  = tid >> 18;          // batch group 0..7
    int s   = sd >> 6;            // sequence position (uniform per wave)
    int d4  = sd & 63;            // float4 index within row
    int d0  = d4 * 4;             // dims d0(e), d0+1(o), d0+2(e), d0+3(o)

    // pe for this thread's 4 dims (precise math: args up to ~4095 rad)
    float f0 = powf(10000.0f, -(float)d0       / (float)DIM);
    float f2 = powf(10000.0f, -(float)(d0 + 2) / (float)DIM);
    float p  = (float)s;
    float s0, c0, s2, c2;
    sincosf(p * f0, &s0, &c0);
    sincosf(p * f2, &s2, &c2);
    f32x4 pe;
    pe.x = s0; pe.y = c0; pe.z = s2; pe.w = c2;

    const int b0 = bg * BPT;

    // issue all token loads first (independent, wave-uniform broadcasts)
    int tok[BPT];
    #pragma unroll
    for (int i = 0; i < BPT; ++i)
        tok[i] = x[(b0 + i) * SEQ + s];

    #pragma unroll
    for (int i = 0; i < BPT; ++i) {
        f32x4 w = W4[(size_t)tok[i] * D4 + d4];           // coalesced row gather
        f32x4 o = w + pe;
        out4[((size_t)(b0 + i) * SEQ + s) * D4 + d4] = o; // PLAIN coalesced store
    }
}

extern "C" void kernel_launch(void* const* d_in, const int* in_sizes, int n_in,
                              void* d_out, int out_size, void* d_ws, size_t ws_size,
                              hipStream_t stream) {
    const int*   x = (const int*)d_in[0];      // [32, 4096] token ids
    const float* W = (const float*)d_in[1];    // [50257, 256] fp32
    float*     out = (float*)d_out;            // [32, 4096, 256] fp32

    const int total = SD * NGRP;               // 2,097,152 threads
    const int block = 256;
    const int grid  = total / block;           // 8192 blocks
    pwe_kernel<<<grid, block, 0, stream>>>(x, (const f32x4*)W, (f32x4*)out);
}